// Round 4
// baseline (274.067 us; speedup 1.0000x reference)
//
#include <hip/hip_runtime.h>
#include <hip/hip_cooperative_groups.h>

namespace cg = cooperative_groups;

#define PENALTY_LAMBDA 0.5f
#define RULES 512
#define NR 4            // token ranges
#define RS 32000        // tokens per range (NR*RS == VOCAB)
#define VOCAB 128000
#define G 64            // scatter blocks per range
#define NB 64           // batch rows
#define CH 500          // pen floats per chunk (256 chunks)
#define CJ 125          // f32x4 per chunk

typedef float    f32x4 __attribute__((ext_vector_type(4)));
typedef _Float16 f16x4 __attribute__((ext_vector_type(4)));

// ws layout: partials[NR][G][RS] (fp16) | masks[G][16] (u32)
// Single cooperative kernel: 256 blocks x 1024 threads, 1 block/CU.
// Phase 1 = LDS-histogram scatter; grid.sync; Phase 2 = reduce+loss+stream.
__global__ void __launch_bounds__(1024) mega_kernel(
    const int* __restrict__ rule_ids, const int* __restrict__ token_ids,
    const float* __restrict__ gate_logits, const float* __restrict__ logits,
    _Float16* __restrict__ partials, unsigned* __restrict__ masks,
    float* __restrict__ out_mod, float* __restrict__ out_pen,
    float* __restrict__ out_loss, int E) {
    __shared__ __align__(16) float lds[32640];   // phase1: hist|s_g|s_f; phase2: s_pc|s_part
    __shared__ unsigned s_mask[16];
    __shared__ float sg[8], sf[8];
    int t = threadIdx.x;
    int bid = blockIdx.x;

    // ---------------- phase 1: scatter (bid -> g = bid&63, r = bid>>6) ------
    {
        float* hist = lds;                               // [32000]
        float* s_g  = lds + 32000;                       // [512]
        unsigned char* s_f = (unsigned char*)(lds + 32512); // [512] bytes
        int g = bid & 63, r = bid >> 6;
        for (int i = t * 4; i < RS; i += 1024 * 4)
            *(f32x4*)(hist + i) = (f32x4){0.f, 0.f, 0.f, 0.f};
        if (t < RULES)
            s_g[t] = PENALTY_LAMBDA / (1.0f + expf(-gate_logits[t]));
        if (t >= 512 && t < 512 + RULES / 4) ((unsigned*)s_f)[t - 512] = 0u;
        __syncthreads();

        const int lo = r * RS;
        const int stride = G * 1024 * 4;
        for (int base = (g * 1024 + t) * 4; base + 4 <= E; base += stride) {
            int4 tt = *(const int4*)(token_ids + base);
            int4 rr = *(const int4*)(rule_ids + base);
            int ts[4] = {tt.x, tt.y, tt.z, tt.w};
            int rv[4] = {rr.x, rr.y, rr.z, rr.w};
#pragma unroll
            for (int k = 0; k < 4; ++k) {
                int tok = ts[k] - lo;
                if ((unsigned)tok < (unsigned)RS)
                    unsafeAtomicAdd(&hist[tok], s_g[rv[k]]);
                if (r == 0) s_f[rv[k]] = 1;
            }
        }
        if (g == 0 && t == 0) {            // scalar tail (E % 4) per range
            for (int e = E & ~3; e < E; ++e) {
                int tok = token_ids[e] - lo; int ru = rule_ids[e];
                if ((unsigned)tok < (unsigned)RS)
                    unsafeAtomicAdd(&hist[tok], s_g[ru]);
                if (r == 0) s_f[ru] = 1;
            }
        }
        __syncthreads();

        _Float16* dst = partials + ((size_t)r * G + g) * RS;
        for (int i = t * 4; i < RS; i += 1024 * 4) {
            f32x4 s = *(const f32x4*)(&hist[i]);
            f16x4 h = {(_Float16)s.x, (_Float16)s.y, (_Float16)s.z, (_Float16)s.w};
            *(f16x4*)(dst + i) = h;
        }
        if (r == 0 && t < 16) {
            const unsigned* w = (const unsigned*)s_f + t * 8;
            unsigned m = 0;
#pragma unroll
            for (int k = 0; k < 8; ++k) {
                unsigned d = w[k];
                if (d & 0x000000FFu) m |= 1u << (k * 4 + 0);
                if (d & 0x0000FF00u) m |= 1u << (k * 4 + 1);
                if (d & 0x00FF0000u) m |= 1u << (k * 4 + 2);
                if (d & 0xFF000000u) m |= 1u << (k * 4 + 3);
            }
            masks[g * 16 + t] = m;
        }
    }

    __threadfence();                 // device-scope release of partials+masks
    cg::this_grid().sync();

    // ---------------- phase 2: reduce + loss + stream (bid == chunk) --------
    int chunk = bid;                 // 0..255
    int c0 = chunk * CH;
    int tx = t & 127, ty = t >> 7;   // 128 x 8
    float* s_pc   = lds;             // [504]
    f32x4* s_part = (f32x4*)(lds + 512);   // [8][126]
    {
        int r = c0 / RS;             // 64 chunks per range; never crosses
        int bin = c0 - r * RS;
        if (tx < CJ) {
            f32x4 acc = {0.f, 0.f, 0.f, 0.f};
            const _Float16* bp = partials + ((size_t)r * G + ty * 8) * RS
                               + bin + tx * 4;
#pragma unroll
            for (int gg = 0; gg < 8; ++gg) {
                f16x4 h = *(const f16x4*)(bp + (size_t)gg * RS);
                acc += (f32x4){(float)h.x, (float)h.y, (float)h.z, (float)h.w};
            }
            s_part[ty * 126 + tx] = acc;
        } else if (tx == 127) {
            // 4 lookahead bins (c0+500 .. c0+503), may cross range / wrap
            f32x4 e = {0.f, 0.f, 0.f, 0.f};
            for (int i = 0; i < 4; ++i) {
                int gb = c0 + CH + i; if (gb >= VOCAB) gb -= VOCAB;
                int r2 = gb / RS, b2 = gb - r2 * RS;
                const _Float16* bp2 = partials + ((size_t)r2 * G + ty * 8) * RS + b2;
                float s = 0.f;
                for (int gg = 0; gg < 8; ++gg) s += (float)bp2[(size_t)gg * RS];
                ((float*)&e)[i] = s;
            }
            s_part[ty * 126 + CJ] = e;
        }
    }
    __syncthreads();
    if (t < CJ + 1) {
        f32x4 s = {0.f, 0.f, 0.f, 0.f};
#pragma unroll
        for (int j = 0; j < 8; ++j) s += s_part[j * 126 + t];
        *(f32x4*)(s_pc + t * 4) = s;
    }
    __syncthreads();

    // --- loss: chunk 0 only (block-uniform) ---
    if (chunk == 0) {
        if (t < 16) {
            unsigned m = 0;
            for (int gg = 0; gg < G; ++gg) m |= masks[gg * 16 + t];
            s_mask[t] = m;
        }
        __syncthreads();
        if (t < RULES) {
            float f = ((s_mask[t >> 5] >> (t & 31)) & 1u) ? 1.f : 0.f;
            float gf = f / (1.f + expf(-gate_logits[t]));
            for (int off = 32; off > 0; off >>= 1) {
                gf += __shfl_down(gf, off, 64);
                f  += __shfl_down(f,  off, 64);
            }
            if ((t & 63) == 0) { sg[t >> 6] = gf; sf[t >> 6] = f; }
        }
        __syncthreads();
        if (t == 0) {
            float tg = 0.f, tf = 0.f;
            for (int w = 0; w < 8; ++w) { tg += sg[w]; tf += sf[w]; }
            *out_loss = -tg / fmaxf(tf, 1.0f);
            out_pen[0] = s_pc[0];
            out_pen[1] = s_pc[1];
            out_pen[2] = s_pc[2];
        }
    }

    // --- stream: 64 rows, 8 in flight (ty), 125 f32x4 columns (tx) ---
    if (tx >= CJ) return;
    f32x4 p0 = *(const f32x4*)(s_pc + tx * 4);
    f32x4 ps = {s_pc[tx * 4 + 3], s_pc[tx * 4 + 4],
                s_pc[tx * 4 + 5], s_pc[tx * 4 + 6]};
    bool glast = (chunk == 255 && tx == CJ - 1);
    size_t col = (size_t)c0 + tx * 4;
#pragma unroll
    for (int ib = 0; ib < NB / 8; ++ib) {
        int b = ib * 8 + ty;
        size_t base = (size_t)b * VOCAB + col;
        f32x4 l = __builtin_nontemporal_load((const f32x4*)(logits + base));
        __builtin_nontemporal_store(l - p0, (f32x4*)(out_mod + base));
        if (glast && b == NB - 1) {
            out_pen[base + 3] = p0.w;      // final element, no overrun
        } else {
            // offset in out: BV+1 + b*V + 4j+3 == 0 (mod 4) -> 16B aligned
            __builtin_nontemporal_store(ps, (f32x4*)(out_pen + base + 3));
        }
    }
}

extern "C" void kernel_launch(void* const* d_in, const int* in_sizes, int n_in,
                              void* d_out, int out_size, void* d_ws, size_t ws_size,
                              hipStream_t stream) {
    const float* logits      = (const float*)d_in[0];
    const float* gate_logits = (const float*)d_in[1];
    const int*   rule_ids    = (const int*)d_in[2];
    const int*   token_ids   = (const int*)d_in[3];
    float* out = (float*)d_out;

    int E = in_sizes[2];               // 1,000,000
    const size_t BV = (size_t)NB * VOCAB;

    _Float16* partials = (_Float16*)d_ws;
    unsigned* masks    = (unsigned*)(partials + (size_t)NR * G * RS);

    float* out_mod  = out;
    float* out_pen  = out + BV + 1;
    float* out_loss = out + BV;

    void* kargs[] = {
        (void*)&rule_ids, (void*)&token_ids, (void*)&gate_logits, (void*)&logits,
        (void*)&partials, (void*)&masks,
        (void*)&out_mod, (void*)&out_pen, (void*)&out_loss, (void*)&E
    };
    hipLaunchCooperativeKernel((const void*)mega_kernel, dim3(G * NR), dim3(1024),
                               kargs, 0, stream);
}

// Round 5
// 137.892 us; speedup vs baseline: 1.9875x; 1.9875x over previous
//
#include <hip/hip_runtime.h>

#define PENALTY_LAMBDA 0.5f
#define RULES 512
#define NR 4            // token ranges
#define RS 32000        // tokens per range (NR*RS == VOCAB)
#define VOCAB 128000
#define G 64            // scatter blocks per range
#define NB 64           // batch rows
#define CH 500          // pen floats per fused-kernel chunk (256 chunks)
#define CJ 125          // f32x4 per chunk
#define PB 512          // partition blocks
#define PT 256          // partition threads
#define PW (PB * PT / 64)   // 2048 partition waves

typedef float    f32x4 __attribute__((ext_vector_type(4)));
typedef _Float16 f16x4 __attribute__((ext_vector_type(4)));

// ws: bucket u32[4][PW*wcap] | cnts u32[PW*4] | masks u32[PB*16] | partials fp16[NR][G][RS]

// --- K0: partition. Each pair read ONCE, packed (tok-lo)|rule<<15, compacted
// into 4 range buckets at per-wave reserved slots via ballot (atomic-free). ---
__global__ void __launch_bounds__(PT) part_kernel(
    const int* __restrict__ rule_ids, const int* __restrict__ token_ids,
    unsigned* __restrict__ bucket, unsigned* __restrict__ cnts,
    unsigned* __restrict__ masks, int E, int iters, int wcap) {
    __shared__ unsigned char s_f[RULES];
    int t = threadIdx.x, bid = blockIdx.x;
    if (t < RULES / 4) ((unsigned*)s_f)[t] = 0u;
    __syncthreads();
    int lane = t & 63;
    int wid = bid * (PT / 64) + (t >> 6);          // 0..PW-1
    unsigned long long ltm = (1ULL << lane) - 1ULL;
    unsigned cap = (unsigned)PW * (unsigned)wcap;  // per-range bucket capacity
    unsigned wbase = (unsigned)wid * (unsigned)wcap;
    unsigned w0 = 0, w1 = 0, w2 = 0, w3 = 0;

    for (int it = 0; it < iters; ++it) {
        int i = bid * PT + t + it * (PB * PT);     // wave-coalesced
        bool v = i < E;
        int tok = 0, ru = 0;
        if (v) { tok = token_ids[i]; ru = rule_ids[i]; s_f[ru] = 1; }
        int r = (unsigned)tok / RS;                // 0..3 (magic-mul div)
        unsigned p = (unsigned)(tok - r * RS) | ((unsigned)ru << 15);
#define PART_RANGE(RR, W)                                                  \
        { unsigned long long m = __ballot(v && r == RR);                   \
          if (m) { int pos = __popcll(m & ltm);                            \
                   if (v && r == RR) bucket[RR * cap + wbase + W + pos] = p;\
                   W += (unsigned)__popcll(m); } }
        PART_RANGE(0, w0) PART_RANGE(1, w1) PART_RANGE(2, w2) PART_RANGE(3, w3)
#undef PART_RANGE
    }
    if (lane == 0) {
        unsigned* c = cnts + wid * 4;
        c[0] = w0; c[1] = w1; c[2] = w2; c[3] = w3;
    }
    __syncthreads();
    if (t < 16) {                      // firing bitmask, per-block plain store
        const unsigned* w = (const unsigned*)s_f + t * 8;
        unsigned m = 0;
#pragma unroll
        for (int k = 0; k < 8; ++k) {
            unsigned d = w[k];
            if (d & 0x000000FFu) m |= 1u << (k * 4 + 0);
            if (d & 0x0000FF00u) m |= 1u << (k * 4 + 1);
            if (d & 0x00FF0000u) m |= 1u << (k * 4 + 2);
            if (d & 0xFF000000u) m |= 1u << (k * 4 + 3);
        }
        masks[bid * 16 + t] = m;
    }
}

// --- K1: scatter from pre-partitioned buckets (no predication waste). ---
__global__ void __launch_bounds__(1024) scatter_kernel(
    const unsigned* __restrict__ bucket, const unsigned* __restrict__ cnts,
    const float* __restrict__ gate_logits, _Float16* __restrict__ partials,
    int wcap) {
    __shared__ __align__(16) float hist[RS];
    __shared__ float s_g[RULES];
    int t = threadIdx.x;
    int g = blockIdx.x;    // 0..G-1
    int r = blockIdx.y;    // 0..NR-1
    for (int i = t * 4; i < RS; i += 1024 * 4)
        *(f32x4*)(hist + i) = (f32x4){0.f, 0.f, 0.f, 0.f};
    if (t < RULES)
        s_g[t] = PENALTY_LAMBDA / (1.0f + expf(-gate_logits[t]));
    __syncthreads();

    unsigned cap = (unsigned)PW * (unsigned)wcap;
    const int WPB = PW / G;                       // 32 partition waves / block
    for (int w = 0; w < WPB; ++w) {
        int wid = g * WPB + w;
        unsigned cnt = cnts[wid * 4 + r];
        const unsigned* bp = bucket + r * cap + (unsigned)wid * (unsigned)wcap;
        for (unsigned i = t; i < cnt; i += 1024) {
            unsigned p = bp[i];
            unsafeAtomicAdd(&hist[p & 32767u], s_g[p >> 15]);
        }
    }
    __syncthreads();

    // stream partial histogram out as fp16 (halves IC round-trip traffic)
    _Float16* dst = partials + ((size_t)r * G + g) * RS;
    for (int i = t * 4; i < RS; i += 1024 * 4) {
        f32x4 s = *(const f32x4*)(&hist[i]);
        f16x4 h = {(_Float16)s.x, (_Float16)s.y, (_Float16)s.z, (_Float16)s.w};
        *(f16x4*)(dst + i) = h;
    }
}

// --- K2: fused reduce + loss + broadcast (R0 structure, proven). ---
__global__ void __launch_bounds__(512) fused_kernel(
    const _Float16* __restrict__ partials, const unsigned* __restrict__ masks,
    const float* __restrict__ gate_logits, const float* __restrict__ logits,
    float* __restrict__ out_mod, float* __restrict__ out_pen,
    float* __restrict__ out_loss) {
    __shared__ float s_pc[CH + 4];         // pen chunk + 4 lookahead floats
    __shared__ f32x4 s_part[4][CJ + 1];    // per-ty partial sums
    int t = threadIdx.x;
    int tx = t & 127, ty = t >> 7;         // 128 x 4
    int chunk = blockIdx.x;                // 0..255
    int c0 = chunk * CH;
    int r = c0 / RS;                       // 64 chunks per range; never crosses
    int bin = c0 - r * RS;

    // --- phase A: pen chunk = sum over G fp16 partials (each ty sums 16) ---
    {
        if (tx < CJ) {
            f32x4 acc = {0.f, 0.f, 0.f, 0.f};
            const _Float16* bp = partials + ((size_t)r * G + ty * 16) * RS
                               + bin + tx * 4;
#pragma unroll 4
            for (int g = 0; g < 16; ++g) {
                f16x4 h = *(const f16x4*)(bp + (size_t)g * RS);
                acc += (f32x4){(float)h.x, (float)h.y, (float)h.z, (float)h.w};
            }
            s_part[ty][tx] = acc;
        } else if (tx == 127) {
            // 4 lookahead bins (c0+500 .. c0+503), may cross range / wrap
            f32x4 e = {0.f, 0.f, 0.f, 0.f};
            for (int i = 0; i < 4; ++i) {
                int gb = c0 + CH + i; if (gb >= VOCAB) gb -= VOCAB;
                int r2 = gb / RS, b2 = gb - r2 * RS;
                const _Float16* bp2 = partials + ((size_t)r2 * G + ty * 16) * RS + b2;
                float s = 0.f;
                for (int g = 0; g < 16; ++g) s += (float)bp2[(size_t)g * RS];
                ((float*)&e)[i] = s;
            }
            s_part[ty][CJ] = e;
        }
    }
    __syncthreads();
    if (t < CJ + 1) {
        f32x4 s = s_part[0][t] + s_part[1][t] + s_part[2][t] + s_part[3][t];
        *(f32x4*)(s_pc + t * 4) = s;
    }
    __syncthreads();

    // --- loss: chunk 0 only (block-uniform) ---
    if (chunk == 0) {
        __shared__ unsigned s_mask[16];
        __shared__ float sg[8], sf[8];
        if (t < 16) {
            unsigned m = 0;
            for (int g = 0; g < PB; ++g) m |= masks[g * 16 + t];
            s_mask[t] = m;
        }
        __syncthreads();
        float f = ((s_mask[t >> 5] >> (t & 31)) & 1u) ? 1.f : 0.f;
        float gf = f / (1.f + expf(-gate_logits[t]));   // t < 512 == RULES
        for (int off = 32; off > 0; off >>= 1) {
            gf += __shfl_down(gf, off, 64);
            f  += __shfl_down(f,  off, 64);
        }
        if ((t & 63) == 0) { sg[t >> 6] = gf; sf[t >> 6] = f; }
        __syncthreads();
        if (t == 0) {
            float tg = 0.f, tf = 0.f;
            for (int w = 0; w < 8; ++w) { tg += sg[w]; tf += sf[w]; }
            *out_loss = -tg / fmaxf(tf, 1.0f);
            // head of flat pen region (out_pen == out + BV + 1)
            out_pen[0] = s_pc[0];
            out_pen[1] = s_pc[1];
            out_pen[2] = s_pc[2];
        }
    }

    // --- phase B: stream 64 rows, 4 in flight (ty), 125 f32x4 columns (tx) ---
    if (tx >= CJ) return;
    f32x4 p0 = *(const f32x4*)(s_pc + tx * 4);
    f32x4 ps = {s_pc[tx * 4 + 3], s_pc[tx * 4 + 4],
                s_pc[tx * 4 + 5], s_pc[tx * 4 + 6]};
    bool glast = (chunk == 255 && tx == CJ - 1);
    size_t col = (size_t)c0 + tx * 4;
#pragma unroll 4
    for (int ib = 0; ib < NB / 4; ++ib) {
        int b = ib * 4 + ty;
        size_t base = (size_t)b * VOCAB + col;
        f32x4 l = *(const f32x4*)(logits + base);
        *(f32x4*)(out_mod + base) = l - p0;
        if (glast && b == NB - 1) {
            out_pen[base + 3] = p0.w;      // final element, no overrun
        } else {
            // offset in out: BV+1 + b*V + 4j+3 == 0 (mod 4) -> 16B aligned
            *(f32x4*)(out_pen + base + 3) = ps;
        }
    }
}

extern "C" void kernel_launch(void* const* d_in, const int* in_sizes, int n_in,
                              void* d_out, int out_size, void* d_ws, size_t ws_size,
                              hipStream_t stream) {
    const float* logits      = (const float*)d_in[0];
    const float* gate_logits = (const float*)d_in[1];
    const int*   rule_ids    = (const int*)d_in[2];
    const int*   token_ids   = (const int*)d_in[3];
    float* out = (float*)d_out;

    const int E = in_sizes[2];           // 1,000,000
    const size_t BV = (size_t)NB * VOCAB;

    int iters = (E + PB * PT - 1) / (PB * PT);   // 8 for E=1e6
    int wcap  = iters * 64;                      // max pairs per partition wave

    unsigned* bucket   = (unsigned*)d_ws;                      // 4 * PW * wcap
    unsigned* cnts     = bucket + (size_t)4 * PW * wcap;       // PW*4
    unsigned* masks    = cnts + (size_t)PW * 4;                // PB*16
    _Float16* partials = (_Float16*)(masks + (size_t)PB * 16); // NR*G*RS fp16

    part_kernel<<<PB, PT, 0, stream>>>(
        rule_ids, token_ids, bucket, cnts, masks, E, iters, wcap);

    scatter_kernel<<<dim3(G, NR), 1024, 0, stream>>>(
        bucket, cnts, gate_logits, partials, wcap);

    fused_kernel<<<VOCAB / CH, 512, 0, stream>>>(
        partials, masks, gate_logits, logits,
        out, out + BV + 1, out + BV);
}

// Round 6
// 119.077 us; speedup vs baseline: 2.3016x; 1.1580x over previous
//
#include <hip/hip_runtime.h>

#define PENALTY_LAMBDA 0.5f
#define RULES 512
#define NR 4            // token ranges
#define RS 32000        // tokens per range (NR*RS == VOCAB)
#define VOCAB 128000
#define G 64            // scatter blocks per range
#define NB 64           // batch rows
#define CH 500          // pen floats per fused-kernel chunk (256 chunks)
#define CJ 125          // f32x4 per chunk

typedef float    f32x4 __attribute__((ext_vector_type(4)));
typedef _Float16 f16x4 __attribute__((ext_vector_type(4)));

// ws layout: partials[NR][G][RS] (fp16) | masks[G][16] (u32)

// --- K1: LDS-histogram scatter, gates fused. grid=(G, NR) x 512 ---
// 8 elements/thread/iter (4 independent int4 loads in flight): halves loop
// trips, doubles MLP vs R0. Blocks (g, r=0..3) share bid mod 8 -> same XCD L2.
__global__ void __launch_bounds__(512) scatter_kernel(
    const int* __restrict__ rule_ids, const int* __restrict__ token_ids,
    const float* __restrict__ gate_logits, _Float16* __restrict__ partials,
    unsigned* __restrict__ masks, int E) {
    __shared__ __align__(16) float hist[RS];
    __shared__ float s_g[RULES];
    __shared__ unsigned char s_f[RULES];
    int t = threadIdx.x;
    int g = blockIdx.x;    // 0..G-1
    int r = blockIdx.y;    // 0..NR-1
    for (int i = t * 4; i < RS; i += 512 * 4)
        *(f32x4*)(hist + i) = (f32x4){0.f, 0.f, 0.f, 0.f};
    if (t < RULES) {
        float x = gate_logits[t];
        s_g[t] = PENALTY_LAMBDA / (1.0f + expf(-x));   // 0.5*sigmoid
    }
    if (t < RULES / 4) ((unsigned*)s_f)[t] = 0u;
    __syncthreads();

    const int lo = r * RS;
    const int stride = G * 512 * 8;
    for (int base = (g * 512 + t) * 8; base + 8 <= E; base += stride) {
        int4 t0 = *(const int4*)(token_ids + base);
        int4 t1 = *(const int4*)(token_ids + base + 4);
        int4 r0 = *(const int4*)(rule_ids + base);
        int4 r1 = *(const int4*)(rule_ids + base + 4);
        int ts[8] = {t0.x, t0.y, t0.z, t0.w, t1.x, t1.y, t1.z, t1.w};
        int rv[8] = {r0.x, r0.y, r0.z, r0.w, r1.x, r1.y, r1.z, r1.w};
#pragma unroll
        for (int k = 0; k < 8; ++k) {
            int tok = ts[k] - lo;
            if ((unsigned)tok < (unsigned)RS) atomicAdd(&hist[tok], s_g[rv[k]]);
            if (r == 0) s_f[rv[k]] = 1;
        }
    }
    if (g == 0 && t == 0) {             // scalar tail (E % 8)
        for (int e = E & ~7; e < E; ++e) {
            int tok = token_ids[e] - lo; int ru = rule_ids[e];
            if ((unsigned)tok < (unsigned)RS) atomicAdd(&hist[tok], s_g[ru]);
            if (r == 0) s_f[ru] = 1;
        }
    }
    __syncthreads();

    // stream partial histogram out as fp16 (halves IC round-trip traffic)
    _Float16* dst = partials + ((size_t)r * G + g) * RS;
    for (int i = t * 4; i < RS; i += 512 * 4) {
        f32x4 s = *(const f32x4*)(&hist[i]);
        f16x4 h = {(_Float16)s.x, (_Float16)s.y, (_Float16)s.z, (_Float16)s.w};
        *(f16x4*)(dst + i) = h;
    }

    // firing bitmask: per-block plain stores (no init, no global atomics)
    if (r == 0 && t < 16) {
        const unsigned* w = (const unsigned*)s_f + t * 8;
        unsigned m = 0;
#pragma unroll
        for (int k = 0; k < 8; ++k) {
            unsigned d = w[k];
            if (d & 0x000000FFu) m |= 1u << (k * 4 + 0);
            if (d & 0x0000FF00u) m |= 1u << (k * 4 + 1);
            if (d & 0x00FF0000u) m |= 1u << (k * 4 + 2);
            if (d & 0xFF000000u) m |= 1u << (k * 4 + 3);
        }
        masks[g * 16 + t] = m;
    }
}

// --- K2: fused reduce + loss + broadcast. 256 persistent blocks; block
// `chunk` owns pen columns [chunk*500, chunk*500+500). ---
__global__ void __launch_bounds__(512) fused_kernel(
    const _Float16* __restrict__ partials, const unsigned* __restrict__ masks,
    const float* __restrict__ gate_logits, const float* __restrict__ logits,
    float* __restrict__ out_mod, float* __restrict__ out_pen,
    float* __restrict__ out_loss) {
    __shared__ float s_pc[CH + 4];         // pen chunk + 4 lookahead floats
    __shared__ f32x4 s_part[4][CJ + 1];    // per-ty partial sums
    int t = threadIdx.x;
    int tx = t & 127, ty = t >> 7;         // 128 x 4
    int chunk = blockIdx.x;                // 0..255
    int c0 = chunk * CH;
    int r = c0 / RS;                       // 64 chunks per range; never crosses
    int bin = c0 - r * RS;

    // --- phase A: pen chunk = sum over G fp16 partials (each ty sums 16) ---
    {
        if (tx < CJ) {
            f32x4 acc = {0.f, 0.f, 0.f, 0.f};
            const _Float16* bp = partials + ((size_t)r * G + ty * 16) * RS
                               + bin + tx * 4;
#pragma unroll                             // full unroll: 16 loads in flight
            for (int g = 0; g < 16; ++g) {
                f16x4 h = *(const f16x4*)(bp + (size_t)g * RS);
                acc += (f32x4){(float)h.x, (float)h.y, (float)h.z, (float)h.w};
            }
            s_part[ty][tx] = acc;
        } else if (tx == 127) {
            // 4 lookahead bins (c0+500 .. c0+503), may cross range / wrap
            f32x4 e = {0.f, 0.f, 0.f, 0.f};
            for (int i = 0; i < 4; ++i) {
                int gb = c0 + CH + i; if (gb >= VOCAB) gb -= VOCAB;
                int r2 = gb / RS, b2 = gb - r2 * RS;
                const _Float16* bp2 = partials + ((size_t)r2 * G + ty * 16) * RS + b2;
                float s = 0.f;
                for (int g = 0; g < 16; ++g) s += (float)bp2[(size_t)g * RS];
                ((float*)&e)[i] = s;
            }
            s_part[ty][CJ] = e;
        }
    }
    __syncthreads();
    if (t < CJ + 1) {
        f32x4 s = s_part[0][t] + s_part[1][t] + s_part[2][t] + s_part[3][t];
        *(f32x4*)(s_pc + t * 4) = s;
    }
    __syncthreads();

    // --- loss: chunk 0 only (block-uniform) ---
    if (chunk == 0) {
        __shared__ unsigned s_mask[16];
        __shared__ float sg[8], sf[8];
        if (t < 16) {
            unsigned m = 0;
            for (int g = 0; g < G; ++g) m |= masks[g * 16 + t];
            s_mask[t] = m;
        }
        __syncthreads();
        float f = ((s_mask[t >> 5] >> (t & 31)) & 1u) ? 1.f : 0.f;
        float gf = f / (1.f + expf(-gate_logits[t]));   // t < 512 == RULES
        for (int off = 32; off > 0; off >>= 1) {
            gf += __shfl_down(gf, off, 64);
            f  += __shfl_down(f,  off, 64);
        }
        if ((t & 63) == 0) { sg[t >> 6] = gf; sf[t >> 6] = f; }
        __syncthreads();
        if (t == 0) {
            float tg = 0.f, tf = 0.f;
            for (int w = 0; w < 8; ++w) { tg += sg[w]; tf += sf[w]; }
            *out_loss = -tg / fmaxf(tf, 1.0f);
            // head of flat pen region (out_pen == out + BV + 1)
            out_pen[0] = s_pc[0];
            out_pen[1] = s_pc[1];
            out_pen[2] = s_pc[2];
        }
    }

    // --- phase B: stream 64 rows, 4 in flight (ty), 125 f32x4 columns (tx) ---
    if (tx >= CJ) return;
    f32x4 p0 = *(const f32x4*)(s_pc + tx * 4);
    f32x4 ps = {s_pc[tx * 4 + 3], s_pc[tx * 4 + 4],
                s_pc[tx * 4 + 5], s_pc[tx * 4 + 6]};
    bool glast = (chunk == 255 && tx == CJ - 1);
    size_t col = (size_t)c0 + tx * 4;
#pragma unroll 4
    for (int ib = 0; ib < NB / 4; ++ib) {
        int b = ib * 4 + ty;
        size_t base = (size_t)b * VOCAB + col;
        f32x4 l = *(const f32x4*)(logits + base);
        *(f32x4*)(out_mod + base) = l - p0;
        if (glast && b == NB - 1) {
            out_pen[base + 3] = p0.w;      // final element, no overrun
        } else {
            // offset in out: BV+1 + b*V + 4j+3 == 0 (mod 4) -> 16B aligned
            *(f32x4*)(out_pen + base + 3) = ps;
        }
    }
}

extern "C" void kernel_launch(void* const* d_in, const int* in_sizes, int n_in,
                              void* d_out, int out_size, void* d_ws, size_t ws_size,
                              hipStream_t stream) {
    const float* logits      = (const float*)d_in[0];
    const float* gate_logits = (const float*)d_in[1];
    const int*   rule_ids    = (const int*)d_in[2];
    const int*   token_ids   = (const int*)d_in[3];
    float* out = (float*)d_out;

    const int E = in_sizes[2];           // 1,000,000
    const size_t BV = (size_t)NB * VOCAB;

    _Float16* partials = (_Float16*)d_ws;
    unsigned* masks    = (unsigned*)(partials + (size_t)NR * G * RS);

    scatter_kernel<<<dim3(G, NR), 512, 0, stream>>>(
        rule_ids, token_ids, gate_logits, partials, masks, E);

    fused_kernel<<<VOCAB / CH, 512, 0, stream>>>(
        partials, masks, gate_logits, logits,
        out, out + BV + 1, out + BV);
}